// Round 8
// baseline (441.574 us; speedup 1.0000x reference)
//
#include <hip/hip_runtime.h>
#include <math.h>

#define NN 25000
#define NE 50000
#define NEP2 50176            // 98 * 512 edges (padded)
#define NATOM 26
#define NUM_ITER 3
#define NCH 33                // K' = 33 chunks x 256 (4 k-values x 64 i's)
#define NPB 32
#define EB2 512               // edges per block (v2)
#define KSP 17                // chunks per K-split block: [0,17) and [17,33)

typedef __attribute__((ext_vector_type(8))) short bf16x8;
typedef __attribute__((ext_vector_type(8))) unsigned short ushort8_t;
typedef __attribute__((ext_vector_type(4))) float f32x4;
union FragU { bf16x8 v; ushort4 q[2]; };

static __device__ __forceinline__ ushort f2bf(float f) {
  unsigned u = __float_as_uint(f);
  unsigned r = (u + 0x7FFFu + ((u >> 16) & 1u)) >> 16;
  return (ushort)r;
}
static __device__ __forceinline__ unsigned cvt_pk_bf16(float a, float b) {
  unsigned r;
  asm("v_cvt_pk_bf16_f32 %0, %1, %2" : "=v"(r) : "v"(a), "v"(b));
  return r;
}
static __device__ __forceinline__ float bflo(unsigned u) { return __uint_as_float(u << 16); }
static __device__ __forceinline__ float bfhi(unsigned u) { return __uint_as_float(u & 0xFFFF0000u); }

// ---------------- U pack: relu(ea@We1+be1) -> Upkt[g][e][4] bf16 (k-group-major)
__global__ __launch_bounds__(256) void edge_mlp_pack_kernel(
    const float* __restrict__ ea, const float* __restrict__ We1,
    const float* __restrict__ be1, ushort* __restrict__ Upkt) {
  int t = threadIdx.x;
  int el = t & 63, seg = t >> 6;
  int e = blockIdx.x * 64 + el;       // grid 784 -> e < 50176
  bool valid = (e < NE);
  float a0 = 0.f, a1 = 0.f, a2 = 0.f, a3 = 0.f;
  if (valid) { a0 = ea[e * 4]; a1 = ea[e * 4 + 1]; a2 = ea[e * 4 + 2]; a3 = ea[e * 4 + 3]; }
  #pragma unroll
  for (int q = 0; q < 8; ++q) {
    int g = seg * 8 + q;              // k-group 0..31 (k = 4g..4g+3 < 128)
    ushort out[4];
    #pragma unroll
    for (int kk = 0; kk < 4; ++kk) {
      int k = g * 4 + kk;
      float v = be1[k];
      v = fmaf(a0, We1[k], v);
      v = fmaf(a1, We1[128 + k], v);
      v = fmaf(a2, We1[256 + k], v);
      v = fmaf(a3, We1[384 + k], v);
      out[kk] = valid ? f2bf(fmaxf(v, 0.f)) : (ushort)0;
    }
    *(ushort4*)&Upkt[((size_t)g * NEP2 + e) * 4] = *(ushort4*)out;
  }
  if (seg == 0) {                     // g=32: k=128 -> 1.0 (be2 fold), 129..131 -> 0
    ushort out[4] = {(ushort)(valid ? 0x3F80 : 0), 0, 0, 0};
    *(ushort4*)&Upkt[((size_t)32 * NEP2 + e) * 4] = *(ushort4*)out;
  }
}

// ---------------- B pack: We2ext[f][o] -> per-lane fragment order
__global__ __launch_bounds__(256) void bpk_pack_kernel(
    const float* __restrict__ We2, const float* __restrict__ be2,
    ushort* __restrict__ Bpk) {
  int idx = blockIdx.x * 256 + threadIdx.x;   // 264 blocks -> 67584 = 33*8*4*64
  int lane = idx & 63;
  int nt = (idx >> 6) & 3;
  int ks = (idx >> 8) & 7;
  int c = idx >> 11;
  int l15 = lane & 15, lg = lane >> 4;
  int o = nt * 16 + l15;
  ushort v[8];
  #pragma unroll
  for (int j = 0; j < 8; ++j) {
    int kl = (j < 4) ? (4 * lg + j) : (12 + 4 * lg + j);   // split-halves k-map
    int f = c * 256 + ks * 32 + kl;
    int k = f >> 6, i = f & 63;
    float wv = 0.f;
    if (k < 128) wv = We2[(size_t)k * 4096 + i * 64 + o];
    else if (k == 128) wv = be2[i * 64 + o];
    v[j] = f2bf(wv);
  }
  *(ushort8_t*)(Bpk + (size_t)idx * 8) = *(ushort8_t*)v;
}

// ---------------- GRU/conv weight pack: fragment-linear bf16 in ws
__global__ __launch_bounds__(256) void nw_pack_kernel(
    const float* __restrict__ W_root, const float* __restrict__ W_ih,
    const float* __restrict__ W_hh, ushort* __restrict__ Wr_pk,
    ushort* __restrict__ Bih_pk, ushort* __restrict__ Bhh_pk) {
  int idx = blockIdx.x * 256 + threadIdx.x;   // 14 blocks -> 3584 frags
  if (idx >= 3584) return;
  int lane, nt, ks, kind;
  ushort* dstp;
  if (idx < 512)      { kind = 0; int f = idx;        lane = f & 63; nt = (f >> 6) % 4;  ks = (f >> 6) / 4;  dstp = Wr_pk  + (size_t)f * 8; }
  else if (idx < 2048){ kind = 1; int f = idx - 512;  lane = f & 63; nt = (f >> 6) % 12; ks = (f >> 6) / 12; dstp = Bih_pk + (size_t)f * 8; }
  else                { kind = 2; int f = idx - 2048; lane = f & 63; nt = (f >> 6) % 12; ks = (f >> 6) / 12; dstp = Bhh_pk + (size_t)f * 8; }
  int l15 = lane & 15, lg = lane >> 4;
  int col = nt * 16 + l15;
  ushort v[8];
  #pragma unroll
  for (int j = 0; j < 8; ++j) {
    int kl = (j < 4) ? (4 * lg + j) : (12 + 4 * lg + j);
    int i = ks * 32 + kl;
    float wv;
    if (kind == 0)      wv = W_root[i * 64 + col];
    else if (kind == 1) wv = W_ih[col * 64 + i];
    else                wv = W_hh[col * 64 + i];
    v[j] = f2bf(wv);
  }
  *(ushort8_t*)dstp = *(ushort8_t*)v;
}

// ---------------- fused edge-message GEMM v2: 512 edges/block, K split in 2
// 512 threads = 8 waves; wave tile = 64 edge-rows (mt=0..3), full N=64 (nt=0..3).
__global__ __launch_bounds__(512, 2) void edge_rgemm2_kernel(
    const ushort* __restrict__ Upkt, const ushort* __restrict__ Bpk,
    const float* __restrict__ hv, const int* __restrict__ src,
    const int* __restrict__ dst, float* __restrict__ agg) {
  __shared__ ushort sB[2][16384];   // 2 x 32KB frag-packed B chunk (2048 frags x 8)
  __shared__ ushort sU[2][2048];    // 2 x 4KB U chunk [512 e][4 k]
  __shared__ ushort sS[512][72];    // 72KB: s bf16, padded row
  int tid = threadIdx.x;            // 0..511
  int lane = tid & 63, w = tid >> 6;
  int l15 = lane & 15, lg = lane >> 4;
  int e0 = blockIdx.x * EB2;        // 98 edge-blocks
  int c0 = blockIdx.y * KSP;        // 0 or 17
  int c1 = (c0 + KSP < NCH) ? (c0 + KSP) : NCH;

  // stage s = bf16(h[src[e]]) for 512 edges
  #pragma unroll
  for (int r = 0; r < 16; ++r) {
    int idx = r * 512 + tid;        // 0..8191 = 512 rows x 16 float4-parts
    int el = idx >> 4, part = idx & 15;
    int e = e0 + el;
    float4 v = make_float4(0.f, 0.f, 0.f, 0.f);
    if (e < NE) v = ((const float4*)hv)[(size_t)src[e] * 16 + part];
    unsigned lo = cvt_pk_bf16(v.x, v.y);
    unsigned hi = cvt_pk_bf16(v.z, v.w);
    *(uint2*)&sS[el][part * 4] = make_uint2(lo, hi);
  }

  // prologue: stage chunk c0 (2048 B-frags + 512-edge U slice)
  ushort8_t rB[4]; uint2 rU;
  {
    const ushort* bs = Bpk + (size_t)c0 * 16384;
    #pragma unroll
    for (int r = 0; r < 4; ++r)
      rB[r] = *(const ushort8_t*)(bs + ((size_t)r * 512 + tid) * 8);
    rU = *(const uint2*)(Upkt + ((size_t)c0 * NEP2 + e0) * 4 + tid * 4);
  }
  #pragma unroll
  for (int r = 0; r < 4; ++r)
    *(ushort8_t*)&sB[0][((size_t)r * 512 + tid) * 8] = rB[r];
  *(uint2*)&sU[0][tid * 4] = rU;
  __syncthreads();

  // per-wave s fragments: row = w*64 + mt*16 + l15, i = p*32 + g*16 + 4*lg
  float4 sreg[4][2][2];
  #pragma unroll
  for (int mt = 0; mt < 4; ++mt)
    #pragma unroll
    for (int p = 0; p < 2; ++p)
      #pragma unroll
      for (int g = 0; g < 2; ++g) {
        uint2 d = *(const uint2*)&sS[w * 64 + mt * 16 + l15][p * 32 + g * 16 + 4 * lg];
        sreg[mt][p][g] = make_float4(bflo(d.x), bfhi(d.x), bflo(d.y), bfhi(d.y));
      }

  f32x4 acc[4][4];
  #pragma unroll
  for (int mt = 0; mt < 4; ++mt)
    #pragma unroll
    for (int nt = 0; nt < 4; ++nt) acc[mt][nt] = (f32x4){0.f, 0.f, 0.f, 0.f};

  for (int c = c0; c < c1; ++c) {
    int cur = (c - c0) & 1;
    bool more = (c + 1 < c1);
    if (more) {  // T14: issue next-chunk loads early
      const ushort* bs = Bpk + (size_t)(c + 1) * 16384;
      #pragma unroll
      for (int r = 0; r < 4; ++r)
        rB[r] = *(const ushort8_t*)(bs + ((size_t)r * 512 + tid) * 8);
      rU = *(const uint2*)(Upkt + ((size_t)(c + 1) * NEP2 + e0) * 4 + tid * 4);
    }
    float uu[4][4];
    #pragma unroll
    for (int mt = 0; mt < 4; ++mt) {
      uint2 d = *(const uint2*)&sU[cur][(w * 64 + mt * 16 + l15) * 4];
      uu[mt][0] = bflo(d.x); uu[mt][1] = bfhi(d.x);
      uu[mt][2] = bflo(d.y); uu[mt][3] = bfhi(d.y);
    }
    #pragma unroll
    for (int ks = 0; ks < 8; ++ks) {
      int p = ks & 1, ku = ks >> 1;
      bf16x8 bfr[4];
      #pragma unroll
      for (int nt = 0; nt < 4; ++nt)
        bfr[nt] = *(const bf16x8*)&sB[cur][(((size_t)ks * 4 + nt) * 64 + lane) * 8];
      #pragma unroll
      for (int mt = 0; mt < 4; ++mt) {
        float u = uu[mt][ku];
        float4 s0 = sreg[mt][p][0], s1 = sreg[mt][p][1];
        union { bf16x8 v; unsigned u32[4]; } af;
        af.u32[0] = cvt_pk_bf16(s0.x * u, s0.y * u);
        af.u32[1] = cvt_pk_bf16(s0.z * u, s0.w * u);
        af.u32[2] = cvt_pk_bf16(s1.x * u, s1.y * u);
        af.u32[3] = cvt_pk_bf16(s1.z * u, s1.w * u);
        #pragma unroll
        for (int nt = 0; nt < 4; ++nt)
          acc[mt][nt] = __builtin_amdgcn_mfma_f32_16x16x32_bf16(af.v, bfr[nt], acc[mt][nt], 0, 0, 0);
      }
    }
    if (more) {  // write-late into the other buffer
      int nb = cur ^ 1;
      #pragma unroll
      for (int r = 0; r < 4; ++r)
        *(ushort8_t*)&sB[nb][((size_t)r * 512 + tid) * 8] = rB[r];
      *(uint2*)&sU[nb][tid * 4] = rU;
    }
    __syncthreads();
  }

  // scatter: D row (within 16-tile) = lg*4 + rr, col = nt*16 + l15
  #pragma unroll
  for (int mt = 0; mt < 4; ++mt) {
    #pragma unroll
    for (int rr = 0; rr < 4; ++rr) {
      int e = e0 + w * 64 + mt * 16 + lg * 4 + rr;
      if (e < NE) {
        int d = dst[e];
        #pragma unroll
        for (int nt = 0; nt < 4; ++nt)
          atomicAdd(&agg[(size_t)d * 64 + nt * 16 + l15], acc[mt][nt][rr]);
      }
    }
  }
}

// ---------------- node input transform
__global__ __launch_bounds__(256) void node_in_kernel(
    const float* __restrict__ x, const float* __restrict__ W_in,
    const float* __restrict__ b_in, float* __restrict__ h) {
  int idx = blockIdx.x * 256 + threadIdx.x;
  if (idx >= NN * 64) return;
  int n = idx >> 6, c = idx & 63;
  float acc = b_in[c];
  #pragma unroll
  for (int j = 0; j < NATOM; ++j) acc = fmaf(x[n * NATOM + j], W_in[j * 64 + c], acc);
  h[idx] = fmaxf(acc, 0.f);
}

// ---------------- node update v2: MFMA GRU. 128 nodes/block, 256 thr (4 waves x 32 nodes)
__global__ __launch_bounds__(256, 1) void node_update2_kernel(
    float* __restrict__ hv, const float* __restrict__ agg,
    const ushort* __restrict__ Wr_pk, const ushort* __restrict__ Bih_pk,
    const ushort* __restrict__ Bhh_pk, const float* __restrict__ b_conv,
    const float* __restrict__ b_ih, const float* __restrict__ b_hh) {
  __shared__ ushort h_lds[128][72];   // 18 KB
  __shared__ ushort m_lds[128][72];   // 18 KB
  int tid = threadIdx.x;
  int lane = tid & 63, w = tid >> 6;
  int l15 = lane & 15, lg = lane >> 4;
  int n0 = blockIdx.x * 128;

  #pragma unroll
  for (int r = 0; r < 8; ++r) {
    int idx = r * 256 + tid;
    int row = idx >> 4, part = idx & 15;
    int n = n0 + row;
    float4 v = make_float4(0.f, 0.f, 0.f, 0.f);
    if (n < NN) v = ((const float4*)hv)[(size_t)n * 16 + part];
    *(uint2*)&h_lds[row][part * 4] =
        make_uint2(cvt_pk_bf16(v.x, v.y), cvt_pk_bf16(v.z, v.w));
  }
  __syncthreads();

  bf16x8 ah[2][2];
  #pragma unroll
  for (int mt = 0; mt < 2; ++mt)
    #pragma unroll
    for (int ks = 0; ks < 2; ++ks) {
      int row = w * 32 + mt * 16 + l15;
      FragU f;
      f.q[0] = *(const ushort4*)&h_lds[row][ks * 32 + 4 * lg];
      f.q[1] = *(const ushort4*)&h_lds[row][ks * 32 + 16 + 4 * lg];
      ah[mt][ks] = f.v;
    }

  f32x4 accm[2][4];
  #pragma unroll
  for (int mt = 0; mt < 2; ++mt)
    #pragma unroll
    for (int nt = 0; nt < 4; ++nt) accm[mt][nt] = (f32x4){0.f, 0.f, 0.f, 0.f};
  #pragma unroll
  for (int ks = 0; ks < 2; ++ks)
    #pragma unroll
    for (int nt = 0; nt < 4; ++nt) {
      bf16x8 b = *(const bf16x8*)(Wr_pk + ((size_t)((ks * 4 + nt) * 64 + lane)) * 8);
      #pragma unroll
      for (int mt = 0; mt < 2; ++mt)
        accm[mt][nt] = __builtin_amdgcn_mfma_f32_16x16x32_bf16(ah[mt][ks], b, accm[mt][nt], 0, 0, 0);
    }
  #pragma unroll
  for (int mt = 0; mt < 2; ++mt)
    #pragma unroll
    for (int nt = 0; nt < 4; ++nt) {
      int col = nt * 16 + l15;
      float bc = b_conv[col];
      #pragma unroll
      for (int rr = 0; rr < 4; ++rr) {
        int row = w * 32 + mt * 16 + lg * 4 + rr;
        int n = n0 + row;
        float val = 0.f;
        if (n < NN) val = fmaxf(accm[mt][nt][rr] + agg[(size_t)n * 64 + col] + bc, 0.f);
        m_lds[row][col] = f2bf(val);
      }
    }
  __syncthreads();

  bf16x8 am[2][2];
  #pragma unroll
  for (int mt = 0; mt < 2; ++mt)
    #pragma unroll
    for (int ks = 0; ks < 2; ++ks) {
      int row = w * 32 + mt * 16 + l15;
      FragU f;
      f.q[0] = *(const ushort4*)&m_lds[row][ks * 32 + 4 * lg];
      f.q[1] = *(const ushort4*)&m_lds[row][ks * 32 + 16 + 4 * lg];
      am[mt][ks] = f.v;
    }

  f32x4 acc_s[2][8], acc_in[2][4], acc_hn[2][4];
  #pragma unroll
  for (int mt = 0; mt < 2; ++mt) {
    #pragma unroll
    for (int nt = 0; nt < 8; ++nt) acc_s[mt][nt] = (f32x4){0.f, 0.f, 0.f, 0.f};
    #pragma unroll
    for (int nt = 0; nt < 4; ++nt) {
      acc_in[mt][nt] = (f32x4){0.f, 0.f, 0.f, 0.f};
      acc_hn[mt][nt] = (f32x4){0.f, 0.f, 0.f, 0.f};
    }
  }
  #pragma unroll
  for (int ks = 0; ks < 2; ++ks) {
    #pragma unroll
    for (int nt = 0; nt < 8; ++nt) {
      bf16x8 bi = *(const bf16x8*)(Bih_pk + ((size_t)((ks * 12 + nt) * 64 + lane)) * 8);
      bf16x8 bh = *(const bf16x8*)(Bhh_pk + ((size_t)((ks * 12 + nt) * 64 + lane)) * 8);
      #pragma unroll
      for (int mt = 0; mt < 2; ++mt) {
        acc_s[mt][nt] = __builtin_amdgcn_mfma_f32_16x16x32_bf16(am[mt][ks], bi, acc_s[mt][nt], 0, 0, 0);
        acc_s[mt][nt] = __builtin_amdgcn_mfma_f32_16x16x32_bf16(ah[mt][ks], bh, acc_s[mt][nt], 0, 0, 0);
      }
    }
    #pragma unroll
    for (int nt = 8; nt < 12; ++nt) {
      bf16x8 bi = *(const bf16x8*)(Bih_pk + ((size_t)((ks * 12 + nt) * 64 + lane)) * 8);
      bf16x8 bh = *(const bf16x8*)(Bhh_pk + ((size_t)((ks * 12 + nt) * 64 + lane)) * 8);
      #pragma unroll
      for (int mt = 0; mt < 2; ++mt) {
        acc_in[mt][nt - 8] = __builtin_amdgcn_mfma_f32_16x16x32_bf16(am[mt][ks], bi, acc_in[mt][nt - 8], 0, 0, 0);
        acc_hn[mt][nt - 8] = __builtin_amdgcn_mfma_f32_16x16x32_bf16(ah[mt][ks], bh, acc_hn[mt][nt - 8], 0, 0, 0);
      }
    }
  }

  #pragma unroll
  for (int mt = 0; mt < 2; ++mt)
    #pragma unroll
    for (int nt = 0; nt < 4; ++nt) {
      int col = nt * 16 + l15;
      float b_sr = b_ih[col] + b_hh[col];
      float b_sz = b_ih[64 + col] + b_hh[64 + col];
      float b_in_ = b_ih[128 + col];
      float b_hn = b_hh[128 + col];
      #pragma unroll
      for (int rr = 0; rr < 4; ++rr) {
        int row = w * 32 + mt * 16 + lg * 4 + rr;
        int n = n0 + row;
        if (n >= NN) continue;
        float Sr = acc_s[mt][nt][rr] + b_sr;
        float Sz = acc_s[mt][nt + 4][rr] + b_sz;
        float vin = acc_in[mt][nt][rr] + b_in_;
        float vhn = acc_hn[mt][nt][rr] + b_hn;
        float r = 1.f / (1.f + __expf(-Sr));
        float z = 1.f / (1.f + __expf(-Sz));
        float nn = tanhf(fmaf(r, vhn, vin));
        float hp = hv[(size_t)n * 64 + col];
        hv[(size_t)n * 64 + col] = (1.f - z) * nn + z * hp;
      }
    }
}

// ---------------- head v3: feat only (NO atomics)
__global__ __launch_bounds__(256) void head2_kernel(
    const float* __restrict__ hv, const float* __restrict__ x,
    const float* __restrict__ Wo1, const float* __restrict__ bo1,
    const float* __restrict__ Wo2, const float* __restrict__ bo2,
    float* __restrict__ feat) {
  __shared__ float wo1[64 * 64];
  __shared__ float wo2[64 * 64];
  __shared__ float s_row[NPB * 64];
  __shared__ float s_o1[NPB * 64];
  int tid = threadIdx.x;
  int n0 = blockIdx.x * NPB;

  for (int idx = tid; idx < 64 * 16; idx += 256) {
    ((float4*)wo1)[idx] = ((const float4*)Wo1)[idx];
    ((float4*)wo2)[idx] = ((const float4*)Wo2)[idx];
  }
  for (int idx = tid; idx < NPB * 64; idx += 256) {
    int n = n0 + (idx >> 6);
    s_row[idx] = (n < NN) ? hv[(size_t)n * 64 + (idx & 63)] : 0.f;
  }
  __syncthreads();

  int c = tid & 63, g = tid >> 6;
  #pragma unroll
  for (int q = 0; q < 8; ++q) {
    int nl = g + 4 * q;
    float a = bo1[c];
    for (int i = 0; i < 64; ++i) a = fmaf(s_row[nl * 64 + i], wo1[i * 64 + c], a);
    s_o1[nl * 64 + c] = fmaxf(a, 0.f);
  }
  __syncthreads();
  #pragma unroll
  for (int q = 0; q < 8; ++q) {
    int nl = g + 4 * q;
    int n = n0 + nl;
    float b = bo2[c];
    for (int i = 0; i < 64; ++i) b = fmaf(s_o1[nl * 64 + i], wo2[i * 64 + c], b);
    float xv = (c < NATOM && n < NN) ? x[(size_t)n * NATOM + c] : 0.f;
    float sq = b * b + xv * xv;
    #pragma unroll
    for (int off = 1; off < 64; off <<= 1) sq += __shfl_xor(sq, off);
    if (n >= NN) continue;
    float inv = 1.f / fmaxf(sqrtf(sq), 1e-12f);
    feat[(size_t)n * 90 + c] = b * inv;
    if (c < NATOM) feat[(size_t)n * 90 + 64 + c] = xv * inv;
  }
}

// ---------------- readout: segment mean prep via binary search (no atomics)
static __device__ __forceinline__ int lbound(const int* __restrict__ b, int v) {
  int lo = 0, hi = NN;
  while (lo < hi) { int m = (lo + hi) >> 1; if (b[m] < v) lo = m + 1; else hi = m; }
  return lo;
}

__global__ __launch_bounds__(128) void readout_kernel(
    const float* __restrict__ feat, const int* __restrict__ batch,
    float* __restrict__ readout, float* __restrict__ cnt) {
  __shared__ int bounds[2];
  int g = blockIdx.x;                // 0..63
  int t = threadIdx.x;
  if (t == 0) bounds[0] = lbound(batch, g);
  if (t == 1) bounds[1] = lbound(batch, g + 1);
  __syncthreads();
  int lo = bounds[0], hi = bounds[1];
  if (t < 90) {
    float a0 = 0.f, a1 = 0.f, a2 = 0.f, a3 = 0.f;
    int n = lo;
    for (; n + 3 < hi; n += 4) {
      a0 += feat[(size_t)n * 90 + t];
      a1 += feat[(size_t)(n + 1) * 90 + t];
      a2 += feat[(size_t)(n + 2) * 90 + t];
      a3 += feat[(size_t)(n + 3) * 90 + t];
    }
    for (; n < hi; ++n) a0 += feat[(size_t)n * 90 + t];
    readout[g * 90 + t] = (a0 + a1) + (a2 + a3);
  }
  if (t == 0) cnt[g] = (float)(hi - lo);
}

__global__ __launch_bounds__(64) void ratio_kernel(
    const float* __restrict__ readout, const float* __restrict__ cnt,
    const float* __restrict__ Wp, const float* __restrict__ bp,
    float* __restrict__ ratio) {
  int g = threadIdx.x;
  float c = fmaxf(cnt[g], 1.f);
  float a = bp[0];
  for (int j = 0; j < 90; ++j) a = fmaf(readout[g * 90 + j] / c, Wp[j], a);
  ratio[g] = 1.f / (1.f + __expf(-a));
}

// ==================== launcher ====================

extern "C" void kernel_launch(void* const* d_in, const int* in_sizes, int n_in,
                              void* d_out, int out_size, void* d_ws, size_t ws_size,
                              hipStream_t stream) {
  const float* x      = (const float*)d_in[0];
  const int*   ei     = (const int*)  d_in[1];
  const float* ea     = (const float*)d_in[2];
  const int*   batch  = (const int*)  d_in[3];
  const float* W_in   = (const float*)d_in[4];
  const float* b_in   = (const float*)d_in[5];
  const float* We1    = (const float*)d_in[6];
  const float* be1    = (const float*)d_in[7];
  const float* We2    = (const float*)d_in[8];
  const float* be2    = (const float*)d_in[9];
  const float* W_root = (const float*)d_in[10];
  const float* b_conv = (const float*)d_in[11];
  const float* W_ih   = (const float*)d_in[12];
  const float* b_ih   = (const float*)d_in[13];
  const float* W_hh   = (const float*)d_in[14];
  const float* b_hh   = (const float*)d_in[15];
  const float* Wo1    = (const float*)d_in[16];
  const float* bo1    = (const float*)d_in[17];
  const float* Wo2    = (const float*)d_in[18];
  const float* bo2    = (const float*)d_in[19];
  const float* Wp     = (const float*)d_in[20];
  const float* bp     = (const float*)d_in[21];

  const int* srcp = ei;
  const int* dstp = ei + NE;
  float* feat  = (float*)d_out;
  float* ratio = feat + (size_t)NN * 90;

  // ws layout (bytes): total ~27.2 MB (round-1 proved >= 39.3 MB available)
  char* wsb = (char*)d_ws;
  ushort* Upkt   = (ushort*)(wsb + 0);            // 13,246,464
  ushort* Bpk    = (ushort*)(wsb + 13246464);     //  1,081,344
  float*  h      = (float*) (wsb + 14327808);     //  6,400,000
  float*  agg    = (float*) (wsb + 20727808);     //  6,400,000
  float*  readout= (float*) (wsb + 27127808);     //     23,040
  float*  cnt    = (float*) (wsb + 27150848);     //        256
  ushort* Wr_pk  = (ushort*)(wsb + 27151104);     //      8,192
  ushort* Bih_pk = (ushort*)(wsb + 27159296);     //     24,576
  ushort* Bhh_pk = (ushort*)(wsb + 27183872);     //     24,576  -> 27,208,448 total

  edge_mlp_pack_kernel<<<NEP2 / 64, 256, 0, stream>>>(ea, We1, be1, Upkt);
  bpk_pack_kernel<<<(NCH * 8 * 4 * 64) / 256, 256, 0, stream>>>(We2, be2, Bpk);
  nw_pack_kernel<<<14, 256, 0, stream>>>(W_root, W_ih, W_hh, Wr_pk, Bih_pk, Bhh_pk);
  node_in_kernel<<<(NN * 64 + 255) / 256, 256, 0, stream>>>(x, W_in, b_in, h);

  for (int it = 0; it < NUM_ITER; ++it) {
    hipMemsetAsync(agg, 0, (size_t)NN * 64 * sizeof(float), stream);
    edge_rgemm2_kernel<<<dim3(NEP2 / EB2, 2), 512, 0, stream>>>(
        Upkt, Bpk, h, srcp, dstp, agg);
    node_update2_kernel<<<(NN + 127) / 128, 256, 0, stream>>>(
        h, agg, Wr_pk, Bih_pk, Bhh_pk, b_conv, b_ih, b_hh);
  }

  head2_kernel<<<(NN + NPB - 1) / NPB, 256, 0, stream>>>(
      h, x, Wo1, bo1, Wo2, bo2, feat);
  readout_kernel<<<64, 128, 0, stream>>>(feat, batch, readout, cnt);
  ratio_kernel<<<1, 64, 0, stream>>>(readout, cnt, Wp, bp, ratio);
}

// Round 9
// 420.639 us; speedup vs baseline: 1.0498x; 1.0498x over previous
//
#include <hip/hip_runtime.h>
#include <math.h>

#define NN 25000
#define NE 50000
#define NEP2 50176            // 98 * 512 edges (padded)
#define NATOM 26
#define NUM_ITER 3
#define NCH 33                // K' = 33 chunks x 256 (4 k-values x 64 i's)
#define NPB 32
#define EB2 512               // edges per block
#define KSP 17                // chunks per K-split block: [0,17) and [17,33)

typedef __attribute__((ext_vector_type(8))) short bf16x8;
typedef __attribute__((ext_vector_type(8))) unsigned short ushort8_t;
typedef __attribute__((ext_vector_type(4))) float f32x4;
union FragU { bf16x8 v; ushort4 q[2]; };

static __device__ __forceinline__ ushort f2bf(float f) {
  unsigned u = __float_as_uint(f);
  unsigned r = (u + 0x7FFFu + ((u >> 16) & 1u)) >> 16;
  return (ushort)r;
}
static __device__ __forceinline__ unsigned cvt_pk_bf16(float a, float b) {
  unsigned r;
  asm("v_cvt_pk_bf16_f32 %0, %1, %2" : "=v"(r) : "v"(a), "v"(b));
  return r;
}
static __device__ __forceinline__ float bflo(unsigned u) { return __uint_as_float(u << 16); }
static __device__ __forceinline__ float bfhi(unsigned u) { return __uint_as_float(u & 0xFFFF0000u); }

// ---------------- U pack: relu(ea@We1+be1) -> Upkt[g][e][4] bf16 (k-group-major)
__global__ __launch_bounds__(256) void edge_mlp_pack_kernel(
    const float* __restrict__ ea, const float* __restrict__ We1,
    const float* __restrict__ be1, ushort* __restrict__ Upkt) {
  int t = threadIdx.x;
  int el = t & 63, seg = t >> 6;
  int e = blockIdx.x * 64 + el;       // grid 784 -> e < 50176
  bool valid = (e < NE);
  float a0 = 0.f, a1 = 0.f, a2 = 0.f, a3 = 0.f;
  if (valid) { a0 = ea[e * 4]; a1 = ea[e * 4 + 1]; a2 = ea[e * 4 + 2]; a3 = ea[e * 4 + 3]; }
  #pragma unroll
  for (int q = 0; q < 8; ++q) {
    int g = seg * 8 + q;              // k-group 0..31 (k = 4g..4g+3 < 128)
    ushort out[4];
    #pragma unroll
    for (int kk = 0; kk < 4; ++kk) {
      int k = g * 4 + kk;
      float v = be1[k];
      v = fmaf(a0, We1[k], v);
      v = fmaf(a1, We1[128 + k], v);
      v = fmaf(a2, We1[256 + k], v);
      v = fmaf(a3, We1[384 + k], v);
      out[kk] = valid ? f2bf(fmaxf(v, 0.f)) : (ushort)0;
    }
    *(ushort4*)&Upkt[((size_t)g * NEP2 + e) * 4] = *(ushort4*)out;
  }
  if (seg == 0) {                     // g=32: k=128 -> 1.0 (be2 fold), 129..131 -> 0
    ushort out[4] = {(ushort)(valid ? 0x3F80 : 0), 0, 0, 0};
    *(ushort4*)&Upkt[((size_t)32 * NEP2 + e) * 4] = *(ushort4*)out;
  }
}

// ---------------- B pack: We2ext[f][o] -> per-lane fragment order
__global__ __launch_bounds__(256) void bpk_pack_kernel(
    const float* __restrict__ We2, const float* __restrict__ be2,
    ushort* __restrict__ Bpk) {
  int idx = blockIdx.x * 256 + threadIdx.x;   // 264 blocks -> 67584 = 33*8*4*64
  int lane = idx & 63;
  int nt = (idx >> 6) & 3;
  int ks = (idx >> 8) & 7;
  int c = idx >> 11;
  int l15 = lane & 15, lg = lane >> 4;
  int o = nt * 16 + l15;
  ushort v[8];
  #pragma unroll
  for (int j = 0; j < 8; ++j) {
    int kl = (j < 4) ? (4 * lg + j) : (12 + 4 * lg + j);   // split-halves k-map
    int f = c * 256 + ks * 32 + kl;
    int k = f >> 6, i = f & 63;
    float wv = 0.f;
    if (k < 128) wv = We2[(size_t)k * 4096 + i * 64 + o];
    else if (k == 128) wv = be2[i * 64 + o];
    v[j] = f2bf(wv);
  }
  *(ushort8_t*)(Bpk + (size_t)idx * 8) = *(ushort8_t*)v;
}

// ---------------- GRU/conv weight pack: fragment-linear bf16 in ws
__global__ __launch_bounds__(256) void nw_pack_kernel(
    const float* __restrict__ W_root, const float* __restrict__ W_ih,
    const float* __restrict__ W_hh, ushort* __restrict__ Wr_pk,
    ushort* __restrict__ Bih_pk, ushort* __restrict__ Bhh_pk) {
  int idx = blockIdx.x * 256 + threadIdx.x;   // 14 blocks -> 3584 frags
  if (idx >= 3584) return;
  int lane, nt, ks, kind;
  ushort* dstp;
  if (idx < 512)      { kind = 0; int f = idx;        lane = f & 63; nt = (f >> 6) % 4;  ks = (f >> 6) / 4;  dstp = Wr_pk  + (size_t)f * 8; }
  else if (idx < 2048){ kind = 1; int f = idx - 512;  lane = f & 63; nt = (f >> 6) % 12; ks = (f >> 6) / 12; dstp = Bih_pk + (size_t)f * 8; }
  else                { kind = 2; int f = idx - 2048; lane = f & 63; nt = (f >> 6) % 12; ks = (f >> 6) / 12; dstp = Bhh_pk + (size_t)f * 8; }
  int l15 = lane & 15, lg = lane >> 4;
  int col = nt * 16 + l15;
  ushort v[8];
  #pragma unroll
  for (int j = 0; j < 8; ++j) {
    int kl = (j < 4) ? (4 * lg + j) : (12 + 4 * lg + j);
    int i = ks * 32 + kl;
    float wv;
    if (kind == 0)      wv = W_root[i * 64 + col];
    else if (kind == 1) wv = W_ih[col * 64 + i];
    else                wv = W_hh[col * 64 + i];
    v[j] = f2bf(wv);
  }
  *(ushort8_t*)dstp = *(ushort8_t*)v;
}

// ---------------- fused edge-message GEMM v3: 512 edges/block, 1024 thr (16 waves),
// K split in 2. Wave tile = 32 edge-rows (mt=0..1), full N=64 (nt=0..3).
__global__ __launch_bounds__(1024, 4) void edge_rgemm3_kernel(
    const ushort* __restrict__ Upkt, const ushort* __restrict__ Bpk,
    const float* __restrict__ hv, const int* __restrict__ src,
    const int* __restrict__ dst, float* __restrict__ agg) {
  __shared__ ushort sB[2][16384];   // 2 x 32KB frag-packed B chunk (2048 frags x 8)
  __shared__ ushort sU[2][2048];    // 2 x 4KB U chunk [512 e][4 k]
  __shared__ ushort sS[512][72];    // 72KB: s bf16, padded row
  int tid = threadIdx.x;            // 0..1023
  int lane = tid & 63, w = tid >> 6;  // 16 waves
  int l15 = lane & 15, lg = lane >> 4;
  int e0 = blockIdx.x * EB2;        // 98 edge-blocks
  int c0 = blockIdx.y * KSP;        // 0 or 17
  int c1 = (c0 + KSP < NCH) ? (c0 + KSP) : NCH;

  // stage s = bf16(h[src[e]]) for 512 edges
  #pragma unroll
  for (int r = 0; r < 8; ++r) {
    int idx = r * 1024 + tid;       // 0..8191 = 512 rows x 16 float4-parts
    int el = idx >> 4, part = idx & 15;
    int e = e0 + el;
    float4 v = make_float4(0.f, 0.f, 0.f, 0.f);
    if (e < NE) v = ((const float4*)hv)[(size_t)src[e] * 16 + part];
    unsigned lo = cvt_pk_bf16(v.x, v.y);
    unsigned hi = cvt_pk_bf16(v.z, v.w);
    *(uint2*)&sS[el][part * 4] = make_uint2(lo, hi);
  }

  // prologue: stage chunk c0
  ushort8_t rB[2]; uint2 rU;
  {
    const ushort* bs = Bpk + (size_t)c0 * 16384;
    #pragma unroll
    for (int r = 0; r < 2; ++r)
      rB[r] = *(const ushort8_t*)(bs + ((size_t)r * 1024 + tid) * 8);
    if (tid < 512) rU = *(const uint2*)(Upkt + ((size_t)c0 * NEP2 + e0) * 4 + tid * 4);
  }
  #pragma unroll
  for (int r = 0; r < 2; ++r)
    *(ushort8_t*)&sB[0][((size_t)r * 1024 + tid) * 8] = rB[r];
  if (tid < 512) *(uint2*)&sU[0][tid * 4] = rU;
  __syncthreads();

  // per-wave s fragments: row = w*32 + mt*16 + l15, i = p*32 + g*16 + 4*lg
  float4 sreg[2][2][2];
  #pragma unroll
  for (int mt = 0; mt < 2; ++mt)
    #pragma unroll
    for (int p = 0; p < 2; ++p)
      #pragma unroll
      for (int g = 0; g < 2; ++g) {
        uint2 d = *(const uint2*)&sS[w * 32 + mt * 16 + l15][p * 32 + g * 16 + 4 * lg];
        sreg[mt][p][g] = make_float4(bflo(d.x), bfhi(d.x), bflo(d.y), bfhi(d.y));
      }

  f32x4 acc[2][4];
  #pragma unroll
  for (int mt = 0; mt < 2; ++mt)
    #pragma unroll
    for (int nt = 0; nt < 4; ++nt) acc[mt][nt] = (f32x4){0.f, 0.f, 0.f, 0.f};

  for (int c = c0; c < c1; ++c) {
    int cur = (c - c0) & 1;
    bool more = (c + 1 < c1);
    if (more) {  // T14: issue next-chunk loads early
      const ushort* bs = Bpk + (size_t)(c + 1) * 16384;
      #pragma unroll
      for (int r = 0; r < 2; ++r)
        rB[r] = *(const ushort8_t*)(bs + ((size_t)r * 1024 + tid) * 8);
      if (tid < 512)
        rU = *(const uint2*)(Upkt + ((size_t)(c + 1) * NEP2 + e0) * 4 + tid * 4);
    }
    float uu[2][4];
    #pragma unroll
    for (int mt = 0; mt < 2; ++mt) {
      uint2 d = *(const uint2*)&sU[cur][(w * 32 + mt * 16 + l15) * 4];
      uu[mt][0] = bflo(d.x); uu[mt][1] = bfhi(d.x);
      uu[mt][2] = bflo(d.y); uu[mt][3] = bfhi(d.y);
    }
    #pragma unroll
    for (int ks = 0; ks < 8; ++ks) {
      int p = ks & 1, ku = ks >> 1;
      bf16x8 bfr[4];
      #pragma unroll
      for (int nt = 0; nt < 4; ++nt)
        bfr[nt] = *(const bf16x8*)&sB[cur][(((size_t)ks * 4 + nt) * 64 + lane) * 8];
      #pragma unroll
      for (int mt = 0; mt < 2; ++mt) {
        float u = uu[mt][ku];
        float4 s0 = sreg[mt][p][0], s1 = sreg[mt][p][1];
        union { bf16x8 v; unsigned u32[4]; } af;
        af.u32[0] = cvt_pk_bf16(s0.x * u, s0.y * u);
        af.u32[1] = cvt_pk_bf16(s0.z * u, s0.w * u);
        af.u32[2] = cvt_pk_bf16(s1.x * u, s1.y * u);
        af.u32[3] = cvt_pk_bf16(s1.z * u, s1.w * u);
        #pragma unroll
        for (int nt = 0; nt < 4; ++nt)
          acc[mt][nt] = __builtin_amdgcn_mfma_f32_16x16x32_bf16(af.v, bfr[nt], acc[mt][nt], 0, 0, 0);
      }
    }
    if (more) {  // write-late into the other buffer
      int nb = cur ^ 1;
      #pragma unroll
      for (int r = 0; r < 2; ++r)
        *(ushort8_t*)&sB[nb][((size_t)r * 1024 + tid) * 8] = rB[r];
      if (tid < 512) *(uint2*)&sU[nb][tid * 4] = rU;
    }
    __syncthreads();
  }

  // scatter: D row (within 16-tile) = lg*4 + rr, col = nt*16 + l15
  #pragma unroll
  for (int mt = 0; mt < 2; ++mt) {
    #pragma unroll
    for (int rr = 0; rr < 4; ++rr) {
      int e = e0 + w * 32 + mt * 16 + lg * 4 + rr;
      if (e < NE) {
        int d = dst[e];
        #pragma unroll
        for (int nt = 0; nt < 4; ++nt)
          atomicAdd(&agg[(size_t)d * 64 + nt * 16 + l15], acc[mt][nt][rr]);
      }
    }
  }
}

// ---------------- node input transform
__global__ __launch_bounds__(256) void node_in_kernel(
    const float* __restrict__ x, const float* __restrict__ W_in,
    const float* __restrict__ b_in, float* __restrict__ h) {
  int idx = blockIdx.x * 256 + threadIdx.x;
  if (idx >= NN * 64) return;
  int n = idx >> 6, c = idx & 63;
  float acc = b_in[c];
  #pragma unroll
  for (int j = 0; j < NATOM; ++j) acc = fmaf(x[n * NATOM + j], W_in[j * 64 + c], acc);
  h[idx] = fmaxf(acc, 0.f);
}

// ---------------- node update v2: MFMA GRU. 128 nodes/block, 256 thr (4 waves x 32 nodes)
__global__ __launch_bounds__(256, 1) void node_update2_kernel(
    float* __restrict__ hv, const float* __restrict__ agg,
    const ushort* __restrict__ Wr_pk, const ushort* __restrict__ Bih_pk,
    const ushort* __restrict__ Bhh_pk, const float* __restrict__ b_conv,
    const float* __restrict__ b_ih, const float* __restrict__ b_hh) {
  __shared__ ushort h_lds[128][72];   // 18 KB
  __shared__ ushort m_lds[128][72];   // 18 KB
  int tid = threadIdx.x;
  int lane = tid & 63, w = tid >> 6;
  int l15 = lane & 15, lg = lane >> 4;
  int n0 = blockIdx.x * 128;

  #pragma unroll
  for (int r = 0; r < 8; ++r) {
    int idx = r * 256 + tid;
    int row = idx >> 4, part = idx & 15;
    int n = n0 + row;
    float4 v = make_float4(0.f, 0.f, 0.f, 0.f);
    if (n < NN) v = ((const float4*)hv)[(size_t)n * 16 + part];
    *(uint2*)&h_lds[row][part * 4] =
        make_uint2(cvt_pk_bf16(v.x, v.y), cvt_pk_bf16(v.z, v.w));
  }
  __syncthreads();

  bf16x8 ah[2][2];
  #pragma unroll
  for (int mt = 0; mt < 2; ++mt)
    #pragma unroll
    for (int ks = 0; ks < 2; ++ks) {
      int row = w * 32 + mt * 16 + l15;
      FragU f;
      f.q[0] = *(const ushort4*)&h_lds[row][ks * 32 + 4 * lg];
      f.q[1] = *(const ushort4*)&h_lds[row][ks * 32 + 16 + 4 * lg];
      ah[mt][ks] = f.v;
    }

  f32x4 accm[2][4];
  #pragma unroll
  for (int mt = 0; mt < 2; ++mt)
    #pragma unroll
    for (int nt = 0; nt < 4; ++nt) accm[mt][nt] = (f32x4){0.f, 0.f, 0.f, 0.f};
  #pragma unroll
  for (int ks = 0; ks < 2; ++ks)
    #pragma unroll
    for (int nt = 0; nt < 4; ++nt) {
      bf16x8 b = *(const bf16x8*)(Wr_pk + ((size_t)((ks * 4 + nt) * 64 + lane)) * 8);
      #pragma unroll
      for (int mt = 0; mt < 2; ++mt)
        accm[mt][nt] = __builtin_amdgcn_mfma_f32_16x16x32_bf16(ah[mt][ks], b, accm[mt][nt], 0, 0, 0);
    }
  #pragma unroll
  for (int mt = 0; mt < 2; ++mt)
    #pragma unroll
    for (int nt = 0; nt < 4; ++nt) {
      int col = nt * 16 + l15;
      float bc = b_conv[col];
      #pragma unroll
      for (int rr = 0; rr < 4; ++rr) {
        int row = w * 32 + mt * 16 + lg * 4 + rr;
        int n = n0 + row;
        float val = 0.f;
        if (n < NN) val = fmaxf(accm[mt][nt][rr] + agg[(size_t)n * 64 + col] + bc, 0.f);
        m_lds[row][col] = f2bf(val);
      }
    }
  __syncthreads();

  bf16x8 am[2][2];
  #pragma unroll
  for (int mt = 0; mt < 2; ++mt)
    #pragma unroll
    for (int ks = 0; ks < 2; ++ks) {
      int row = w * 32 + mt * 16 + l15;
      FragU f;
      f.q[0] = *(const ushort4*)&m_lds[row][ks * 32 + 4 * lg];
      f.q[1] = *(const ushort4*)&m_lds[row][ks * 32 + 16 + 4 * lg];
      am[mt][ks] = f.v;
    }

  f32x4 acc_s[2][8], acc_in[2][4], acc_hn[2][4];
  #pragma unroll
  for (int mt = 0; mt < 2; ++mt) {
    #pragma unroll
    for (int nt = 0; nt < 8; ++nt) acc_s[mt][nt] = (f32x4){0.f, 0.f, 0.f, 0.f};
    #pragma unroll
    for (int nt = 0; nt < 4; ++nt) {
      acc_in[mt][nt] = (f32x4){0.f, 0.f, 0.f, 0.f};
      acc_hn[mt][nt] = (f32x4){0.f, 0.f, 0.f, 0.f};
    }
  }
  #pragma unroll
  for (int ks = 0; ks < 2; ++ks) {
    #pragma unroll
    for (int nt = 0; nt < 8; ++nt) {
      bf16x8 bi = *(const bf16x8*)(Bih_pk + ((size_t)((ks * 12 + nt) * 64 + lane)) * 8);
      bf16x8 bh = *(const bf16x8*)(Bhh_pk + ((size_t)((ks * 12 + nt) * 64 + lane)) * 8);
      #pragma unroll
      for (int mt = 0; mt < 2; ++mt) {
        acc_s[mt][nt] = __builtin_amdgcn_mfma_f32_16x16x32_bf16(am[mt][ks], bi, acc_s[mt][nt], 0, 0, 0);
        acc_s[mt][nt] = __builtin_amdgcn_mfma_f32_16x16x32_bf16(ah[mt][ks], bh, acc_s[mt][nt], 0, 0, 0);
      }
    }
    #pragma unroll
    for (int nt = 8; nt < 12; ++nt) {
      bf16x8 bi = *(const bf16x8*)(Bih_pk + ((size_t)((ks * 12 + nt) * 64 + lane)) * 8);
      bf16x8 bh = *(const bf16x8*)(Bhh_pk + ((size_t)((ks * 12 + nt) * 64 + lane)) * 8);
      #pragma unroll
      for (int mt = 0; mt < 2; ++mt) {
        acc_in[mt][nt - 8] = __builtin_amdgcn_mfma_f32_16x16x32_bf16(am[mt][ks], bi, acc_in[mt][nt - 8], 0, 0, 0);
        acc_hn[mt][nt - 8] = __builtin_amdgcn_mfma_f32_16x16x32_bf16(ah[mt][ks], bh, acc_hn[mt][nt - 8], 0, 0, 0);
      }
    }
  }

  #pragma unroll
  for (int mt = 0; mt < 2; ++mt)
    #pragma unroll
    for (int nt = 0; nt < 4; ++nt) {
      int col = nt * 16 + l15;
      float b_sr = b_ih[col] + b_hh[col];
      float b_sz = b_ih[64 + col] + b_hh[64 + col];
      float b_in_ = b_ih[128 + col];
      float b_hn = b_hh[128 + col];
      #pragma unroll
      for (int rr = 0; rr < 4; ++rr) {
        int row = w * 32 + mt * 16 + lg * 4 + rr;
        int n = n0 + row;
        if (n >= NN) continue;
        float Sr = acc_s[mt][nt][rr] + b_sr;
        float Sz = acc_s[mt][nt + 4][rr] + b_sz;
        float vin = acc_in[mt][nt][rr] + b_in_;
        float vhn = acc_hn[mt][nt][rr] + b_hn;
        float r = 1.f / (1.f + __expf(-Sr));
        float z = 1.f / (1.f + __expf(-Sz));
        float nn = tanhf(fmaf(r, vhn, vin));
        float hp = hv[(size_t)n * 64 + col];
        hv[(size_t)n * 64 + col] = (1.f - z) * nn + z * hp;
      }
    }
}

// ---------------- head v3: feat only (NO atomics)
__global__ __launch_bounds__(256) void head2_kernel(
    const float* __restrict__ hv, const float* __restrict__ x,
    const float* __restrict__ Wo1, const float* __restrict__ bo1,
    const float* __restrict__ Wo2, const float* __restrict__ bo2,
    float* __restrict__ feat) {
  __shared__ float wo1[64 * 64];
  __shared__ float wo2[64 * 64];
  __shared__ float s_row[NPB * 64];
  __shared__ float s_o1[NPB * 64];
  int tid = threadIdx.x;
  int n0 = blockIdx.x * NPB;

  for (int idx = tid; idx < 64 * 16; idx += 256) {
    ((float4*)wo1)[idx] = ((const float4*)Wo1)[idx];
    ((float4*)wo2)[idx] = ((const float4*)Wo2)[idx];
  }
  for (int idx = tid; idx < NPB * 64; idx += 256) {
    int n = n0 + (idx >> 6);
    s_row[idx] = (n < NN) ? hv[(size_t)n * 64 + (idx & 63)] : 0.f;
  }
  __syncthreads();

  int c = tid & 63, g = tid >> 6;
  #pragma unroll
  for (int q = 0; q < 8; ++q) {
    int nl = g + 4 * q;
    float a = bo1[c];
    for (int i = 0; i < 64; ++i) a = fmaf(s_row[nl * 64 + i], wo1[i * 64 + c], a);
    s_o1[nl * 64 + c] = fmaxf(a, 0.f);
  }
  __syncthreads();
  #pragma unroll
  for (int q = 0; q < 8; ++q) {
    int nl = g + 4 * q;
    int n = n0 + nl;
    float b = bo2[c];
    for (int i = 0; i < 64; ++i) b = fmaf(s_o1[nl * 64 + i], wo2[i * 64 + c], b);
    float xv = (c < NATOM && n < NN) ? x[(size_t)n * NATOM + c] : 0.f;
    float sq = b * b + xv * xv;
    #pragma unroll
    for (int off = 1; off < 64; off <<= 1) sq += __shfl_xor(sq, off);
    if (n >= NN) continue;
    float inv = 1.f / fmaxf(sqrtf(sq), 1e-12f);
    feat[(size_t)n * 90 + c] = b * inv;
    if (c < NATOM) feat[(size_t)n * 90 + 64 + c] = xv * inv;
  }
}

// ---------------- readout: segment mean prep via binary search (no atomics)
static __device__ __forceinline__ int lbound(const int* __restrict__ b, int v) {
  int lo = 0, hi = NN;
  while (lo < hi) { int m = (lo + hi) >> 1; if (b[m] < v) lo = m + 1; else hi = m; }
  return lo;
}

__global__ __launch_bounds__(128) void readout_kernel(
    const float* __restrict__ feat, const int* __restrict__ batch,
    float* __restrict__ readout, float* __restrict__ cnt) {
  __shared__ int bounds[2];
  int g = blockIdx.x;                // 0..63
  int t = threadIdx.x;
  if (t == 0) bounds[0] = lbound(batch, g);
  if (t == 1) bounds[1] = lbound(batch, g + 1);
  __syncthreads();
  int lo = bounds[0], hi = bounds[1];
  if (t < 90) {
    float a0 = 0.f, a1 = 0.f, a2 = 0.f, a3 = 0.f;
    int n = lo;
    for (; n + 3 < hi; n += 4) {
      a0 += feat[(size_t)n * 90 + t];
      a1 += feat[(size_t)(n + 1) * 90 + t];
      a2 += feat[(size_t)(n + 2) * 90 + t];
      a3 += feat[(size_t)(n + 3) * 90 + t];
    }
    for (; n < hi; ++n) a0 += feat[(size_t)n * 90 + t];
    readout[g * 90 + t] = (a0 + a1) + (a2 + a3);
  }
  if (t == 0) cnt[g] = (float)(hi - lo);
}

__global__ __launch_bounds__(64) void ratio_kernel(
    const float* __restrict__ readout, const float* __restrict__ cnt,
    const float* __restrict__ Wp, const float* __restrict__ bp,
    float* __restrict__ ratio) {
  int g = threadIdx.x;
  float c = fmaxf(cnt[g], 1.f);
  float a = bp[0];
  for (int j = 0; j < 90; ++j) a = fmaf(readout[g * 90 + j] / c, Wp[j], a);
  ratio[g] = 1.f / (1.f + __expf(-a));
}

// ==================== launcher ====================

extern "C" void kernel_launch(void* const* d_in, const int* in_sizes, int n_in,
                              void* d_out, int out_size, void* d_ws, size_t ws_size,
                              hipStream_t stream) {
  const float* x      = (const float*)d_in[0];
  const int*   ei     = (const int*)  d_in[1];
  const float* ea     = (const float*)d_in[2];
  const int*   batch  = (const int*)  d_in[3];
  const float* W_in   = (const float*)d_in[4];
  const float* b_in   = (const float*)d_in[5];
  const float* We1    = (const float*)d_in[6];
  const float* be1    = (const float*)d_in[7];
  const float* We2    = (const float*)d_in[8];
  const float* be2    = (const float*)d_in[9];
  const float* W_root = (const float*)d_in[10];
  const float* b_conv = (const float*)d_in[11];
  const float* W_ih   = (const float*)d_in[12];
  const float* b_ih   = (const float*)d_in[13];
  const float* W_hh   = (const float*)d_in[14];
  const float* b_hh   = (const float*)d_in[15];
  const float* Wo1    = (const float*)d_in[16];
  const float* bo1    = (const float*)d_in[17];
  const float* Wo2    = (const float*)d_in[18];
  const float* bo2    = (const float*)d_in[19];
  const float* Wp     = (const float*)d_in[20];
  const float* bp     = (const float*)d_in[21];

  const int* srcp = ei;
  const int* dstp = ei + NE;
  float* feat  = (float*)d_out;
  float* ratio = feat + (size_t)NN * 90;

  // ws layout (bytes): total ~27.2 MB (round-1 proved >= 39.3 MB available)
  char* wsb = (char*)d_ws;
  ushort* Upkt   = (ushort*)(wsb + 0);            // 13,246,464
  ushort* Bpk    = (ushort*)(wsb + 13246464);     //  1,081,344
  float*  h      = (float*) (wsb + 14327808);     //  6,400,000
  float*  agg    = (float*) (wsb + 20727808);     //  6,400,000
  float*  readout= (float*) (wsb + 27127808);     //     23,040
  float*  cnt    = (float*) (wsb + 27150848);     //        256
  ushort* Wr_pk  = (ushort*)(wsb + 27151104);     //      8,192
  ushort* Bih_pk = (ushort*)(wsb + 27159296);     //     24,576
  ushort* Bhh_pk = (ushort*)(wsb + 27183872);     //     24,576  -> 27,208,448 total

  edge_mlp_pack_kernel<<<NEP2 / 64, 256, 0, stream>>>(ea, We1, be1, Upkt);
  bpk_pack_kernel<<<(NCH * 8 * 4 * 64) / 256, 256, 0, stream>>>(We2, be2, Bpk);
  nw_pack_kernel<<<14, 256, 0, stream>>>(W_root, W_ih, W_hh, Wr_pk, Bih_pk, Bhh_pk);
  node_in_kernel<<<(NN * 64 + 255) / 256, 256, 0, stream>>>(x, W_in, b_in, h);

  for (int it = 0; it < NUM_ITER; ++it) {
    hipMemsetAsync(agg, 0, (size_t)NN * 64 * sizeof(float), stream);
    edge_rgemm3_kernel<<<dim3(NEP2 / EB2, 2), 1024, 0, stream>>>(
        Upkt, Bpk, h, srcp, dstp, agg);
    node_update2_kernel<<<(NN + 127) / 128, 256, 0, stream>>>(
        h, agg, Wr_pk, Bih_pk, Bhh_pk, b_conv, b_ih, b_hh);
  }

  head2_kernel<<<(NN + NPB - 1) / NPB, 256, 0, stream>>>(
      h, x, Wo1, bo1, Wo2, bo2, feat);
  readout_kernel<<<64, 128, 0, stream>>>(feat, batch, readout, cnt);
  ratio_kernel<<<1, 64, 0, stream>>>(readout, cnt, Wp, bp, ratio);
}